// Round 3
// baseline (718.391 us; speedup 1.0000x reference)
//
#include <hip/hip_runtime.h>

#define Nn 4096
#define Cc 256
#define NN2 ((size_t)Nn * Nn)

typedef __attribute__((ext_vector_type(8))) short bf16x8;
typedef __attribute__((ext_vector_type(4))) float f32x4;

__device__ __forceinline__ unsigned short f2bf(float f) {
    union { float f; unsigned u; } v; v.f = f;
    unsigned r = v.u + 0x7FFF + ((v.u >> 16) & 1);
    return (unsigned short)(r >> 16);
}

__device__ __forceinline__ bf16x8 pack2(const float4& a, const float4& b) {
    bf16x8 o;
    o[0] = (short)f2bf(a.x); o[1] = (short)f2bf(a.y);
    o[2] = (short)f2bf(a.z); o[3] = (short)f2bf(a.w);
    o[4] = (short)f2bf(b.x); o[5] = (short)f2bf(b.y);
    o[6] = (short)f2bf(b.z); o[7] = (short)f2bf(b.w);
    return o;
}

// ---------------------------------------------------------------------------
// Kernel 1: V[b,o,n] = bf16( sum_c W[o,c]*X[b,c,n] + bias[o] )
// Fragment-direct, no LDS: A = W rows (k=c contiguous), B = X columns
// (8 strided dwords per fragment). Wave tile 64o x 32n; block 256 thr =
// 4 o-waves (tile 256o x 32n). Grid 4b x 128nt = 512 blocks (2/CU).
// ---------------------------------------------------------------------------
__global__ __launch_bounds__(256) void value_gemm(
    const float* __restrict__ X, const float* __restrict__ W,
    const float* __restrict__ bias, unsigned short* __restrict__ Vout)
{
    const int t = threadIdx.x;
    const int b  = blockIdx.x >> 7;
    const int n0 = (blockIdx.x & 127) << 5;
    const int wave = t >> 6, lane = t & 63;
    const int lrow = lane & 15, lq = lane >> 4;

    const float* Xb = X + (size_t)b * Cc * Nn;
    f32x4 acc[4][2] = {};

    #pragma unroll 2
    for (int k0 = 0; k0 < Cc; k0 += 32) {
        bf16x8 af[4];
        #pragma unroll
        for (int ci = 0; ci < 4; ++ci) {
            const float* wp = W + (size_t)(wave * 64 + ci * 16 + lrow) * Cc + k0 + lq * 8;
            af[ci] = pack2(*(const float4*)wp, *(const float4*)(wp + 4));
        }
        bf16x8 bp[2];
        #pragma unroll
        for (int mi = 0; mi < 2; ++mi) {
            const int n = n0 + mi * 16 + lrow;
            const float* xp = Xb + (size_t)(k0 + lq * 8) * Nn + n;
            bf16x8 o;
            #pragma unroll
            for (int j = 0; j < 8; ++j) o[j] = (short)f2bf(xp[(size_t)j * Nn]);
            bp[mi] = o;
        }
        #pragma unroll
        for (int ci = 0; ci < 4; ++ci)
            #pragma unroll
            for (int mi = 0; mi < 2; ++mi)
                acc[ci][mi] = __builtin_amdgcn_mfma_f32_16x16x32_bf16(
                    af[ci], bp[mi], acc[ci][mi], 0, 0, 0);
    }

    #pragma unroll
    for (int ci = 0; ci < 4; ++ci) {
        #pragma unroll
        for (int rr = 0; rr < 4; ++rr) {
            const int o = wave * 64 + ci * 16 + lq * 4 + rr;
            const float bo = bias[o];
            #pragma unroll
            for (int mi = 0; mi < 2; ++mi) {
                const int n = n0 + mi * 16 + lrow;
                Vout[((size_t)(b * Cc + o)) * Nn + n] = f2bf(acc[ci][mi][rr] + bo);
            }
        }
    }
}

// ---------------------------------------------------------------------------
// Kernel 2: out[b,c,m] = gamma*(sum_n V[c,n]*exp(E[m,n]))/(sum_n exp(E[m,n]))
//                        + 2*X[b,c,m]
// Fragment-direct, NO LDS, NO barriers. B-fragment of exp(E^T) = 8
// contiguous floats of an E row per lane -> load, exp, pack in registers.
// Per-wave online softmax denominator via shfl_xor(16/32).
// Wave tile 64c x 32m; block 256 thr = 4 c-waves (tile 256c x 32m).
// Grid 512 = 4b x 128mt, swizzled so each batch owns 2 XCDs (V stays in
// that XCD's L2). E prefetch distance 2, V prefetch distance 1.
// ---------------------------------------------------------------------------
__global__ __launch_bounds__(256) void attn_gemm(
    const unsigned short* __restrict__ V, const float* __restrict__ E,
    const float* __restrict__ X, const float* __restrict__ gamma,
    float* __restrict__ Out)
{
    const int t = threadIdx.x;
    const int blk = blockIdx.x;
    // blk = j*8 + b*2 + s ; mt = j*2 + s  => XCD (blk%8) fixed per batch
    const int b  = (blk >> 1) & 3;
    const int mt = ((blk >> 3) << 1) + (blk & 1);
    const int m0 = mt << 5;

    const int wave = t >> 6, lane = t & 63;
    const int lrow = lane & 15, lq = lane >> 4;

    const unsigned short* vp[4];
    #pragma unroll
    for (int ci = 0; ci < 4; ++ci)
        vp[ci] = V + ((size_t)(b * Cc + wave * 64 + ci * 16 + lrow)) * Nn + lq * 8;
    const float* ep[2];
    #pragma unroll
    for (int mi = 0; mi < 2; ++mi)
        ep[mi] = E + (size_t)b * NN2 + (size_t)(m0 + mi * 16 + lrow) * Nn + lq * 8;

    f32x4 acc[4][2] = {};
    float sacc[2] = {0.f, 0.f};

    // pipeline registers: E for k (e0) and k+1 (e1); V for k (a0)
    float4 e0[2][2], e1[2][2];
    bf16x8 a0[4];
    #pragma unroll
    for (int mi = 0; mi < 2; ++mi) {
        e0[mi][0] = *(const float4*)(ep[mi]);
        e0[mi][1] = *(const float4*)(ep[mi] + 4);
        e1[mi][0] = *(const float4*)(ep[mi] + 32);
        e1[mi][1] = *(const float4*)(ep[mi] + 36);
    }
    #pragma unroll
    for (int ci = 0; ci < 4; ++ci) a0[ci] = *(const bf16x8*)(vp[ci]);

    #pragma unroll 2
    for (int k = 0; k < 128; ++k) {
        const int ko2 = ((k + 2) & 127) << 5;   // wrap at tail: loaded, never consumed
        const int ko1 = ((k + 1) & 127) << 5;

        // prefetch E for k+2
        float4 en[2][2];
        #pragma unroll
        for (int mi = 0; mi < 2; ++mi) {
            en[mi][0] = *(const float4*)(ep[mi] + ko2);
            en[mi][1] = *(const float4*)(ep[mi] + ko2 + 4);
        }
        // prefetch V for k+1 (L2-resident)
        bf16x8 an[4];
        #pragma unroll
        for (int ci = 0; ci < 4; ++ci) an[ci] = *(const bf16x8*)(vp[ci] + ko1);

        // exp + pack current E; accumulate softmax denominator
        bf16x8 bp[2];
        #pragma unroll
        for (int mi = 0; mi < 2; ++mi) {
            const float s0 = __expf(e0[mi][0].x), s1 = __expf(e0[mi][0].y),
                        s2 = __expf(e0[mi][0].z), s3 = __expf(e0[mi][0].w),
                        s4 = __expf(e0[mi][1].x), s5 = __expf(e0[mi][1].y),
                        s6 = __expf(e0[mi][1].z), s7 = __expf(e0[mi][1].w);
            sacc[mi] += ((s0 + s1) + (s2 + s3)) + ((s4 + s5) + (s6 + s7));
            bf16x8 o;
            o[0] = (short)f2bf(s0); o[1] = (short)f2bf(s1);
            o[2] = (short)f2bf(s2); o[3] = (short)f2bf(s3);
            o[4] = (short)f2bf(s4); o[5] = (short)f2bf(s5);
            o[6] = (short)f2bf(s6); o[7] = (short)f2bf(s7);
            bp[mi] = o;
        }

        #pragma unroll
        for (int ci = 0; ci < 4; ++ci)
            #pragma unroll
            for (int mi = 0; mi < 2; ++mi)
                acc[ci][mi] = __builtin_amdgcn_mfma_f32_16x16x32_bf16(
                    a0[ci], bp[mi], acc[ci][mi], 0, 0, 0);

        // rotate (period-2; unroll 2 renames, no copies)
        #pragma unroll
        for (int mi = 0; mi < 2; ++mi) {
            e0[mi][0] = e1[mi][0]; e0[mi][1] = e1[mi][1];
            e1[mi][0] = en[mi][0]; e1[mi][1] = en[mi][1];
        }
        #pragma unroll
        for (int ci = 0; ci < 4; ++ci) a0[ci] = an[ci];
    }

    // denominator: lanes lrow+{0,16,32,48} together cover all k for row lrow
    #pragma unroll
    for (int mi = 0; mi < 2; ++mi) {
        sacc[mi] += __shfl_xor(sacc[mi], 16);
        sacc[mi] += __shfl_xor(sacc[mi], 32);
    }

    const float g = gamma[0];
    #pragma unroll
    for (int mi = 0; mi < 2; ++mi) {
        const float scale = g / sacc[mi];
        const int m = m0 + mi * 16 + lrow;
        #pragma unroll
        for (int ci = 0; ci < 4; ++ci) {
            #pragma unroll
            for (int rr = 0; rr < 4; ++rr) {
                const int c = wave * 64 + ci * 16 + lq * 4 + rr;
                const size_t off = ((size_t)(b * Cc + c)) * Nn + m;
                Out[off] = scale * acc[ci][mi][rr] + 2.0f * X[off];
            }
        }
    }
}

extern "C" void kernel_launch(void* const* d_in, const int* in_sizes, int n_in,
                              void* d_out, int out_size, void* d_ws, size_t ws_size,
                              hipStream_t stream) {
    const float* energy  = (const float*)d_in[0];  // [4,4096,4096]
    const float* x       = (const float*)d_in[1];  // [4,256,64,64]
    const float* value_w = (const float*)d_in[2];  // [256,256]
    const float* value_b = (const float*)d_in[3];  // [256]
    const float* gamma   = (const float*)d_in[4];  // [1]
    float* out = (float*)d_out;
    unsigned short* Vws = (unsigned short*)d_ws;   // 4*256*4096 bf16 = 8 MB

    value_gemm<<<512, 256, 0, stream>>>(x, value_w, value_b, Vws);
    attn_gemm<<<512, 256, 0, stream>>>(Vws, energy, x, gamma, out);
}

// Round 4
// 452.141 us; speedup vs baseline: 1.5889x; 1.5889x over previous
//
#include <hip/hip_runtime.h>

#define Nn 4096
#define Cc 256
#define NN2 ((size_t)Nn * Nn)

typedef __attribute__((ext_vector_type(8))) short bf16x8;
typedef __attribute__((ext_vector_type(4))) float f32x4;

__device__ __forceinline__ unsigned short f2bf(float f) {
    union { float f; unsigned u; } v; v.f = f;
    unsigned r = v.u + 0x7FFF + ((v.u >> 16) & 1);
    return (unsigned short)(r >> 16);
}

__device__ __forceinline__ bf16x8 pack2(const float4& a, const float4& b) {
    bf16x8 o;
    o[0] = (short)f2bf(a.x); o[1] = (short)f2bf(a.y);
    o[2] = (short)f2bf(a.z); o[3] = (short)f2bf(a.w);
    o[4] = (short)f2bf(b.x); o[5] = (short)f2bf(b.y);
    o[6] = (short)f2bf(b.z); o[7] = (short)f2bf(b.w);
    return o;
}

// exp 8 floats, accumulate into sacc, pack bf16x8, 16B LDS store
__device__ __forceinline__ void expstore(const float4& a, const float4& b,
                                         unsigned short* dst, float& sacc) {
    const float s0 = __expf(a.x), s1 = __expf(a.y), s2 = __expf(a.z), s3 = __expf(a.w);
    const float s4 = __expf(b.x), s5 = __expf(b.y), s6 = __expf(b.z), s7 = __expf(b.w);
    sacc += ((s0 + s1) + (s2 + s3)) + ((s4 + s5) + (s6 + s7));
    bf16x8 o;
    o[0] = (short)f2bf(s0); o[1] = (short)f2bf(s1);
    o[2] = (short)f2bf(s2); o[3] = (short)f2bf(s3);
    o[4] = (short)f2bf(s4); o[5] = (short)f2bf(s5);
    o[6] = (short)f2bf(s6); o[7] = (short)f2bf(s7);
    *(bf16x8*)dst = o;
}

// ---------------------------------------------------------------------------
// Kernel 1: V[b,o,n] = bf16( sum_c W[o,c]*X[b,c,n] + bias[o] )  (as R3)
// ---------------------------------------------------------------------------
__global__ __launch_bounds__(256) void value_gemm(
    const float* __restrict__ X, const float* __restrict__ W,
    const float* __restrict__ bias, unsigned short* __restrict__ Vout)
{
    const int t = threadIdx.x;
    const int b  = blockIdx.x >> 7;
    const int n0 = (blockIdx.x & 127) << 5;
    const int wave = t >> 6, lane = t & 63;
    const int lrow = lane & 15, lq = lane >> 4;

    const float* Xb = X + (size_t)b * Cc * Nn;
    f32x4 acc[4][2] = {};

    #pragma unroll 2
    for (int k0 = 0; k0 < Cc; k0 += 32) {
        bf16x8 af[4];
        #pragma unroll
        for (int ci = 0; ci < 4; ++ci) {
            const float* wp = W + (size_t)(wave * 64 + ci * 16 + lrow) * Cc + k0 + lq * 8;
            af[ci] = pack2(*(const float4*)wp, *(const float4*)(wp + 4));
        }
        bf16x8 bp[2];
        #pragma unroll
        for (int mi = 0; mi < 2; ++mi) {
            const int n = n0 + mi * 16 + lrow;
            const float* xp = Xb + (size_t)(k0 + lq * 8) * Nn + n;
            bf16x8 o;
            #pragma unroll
            for (int j = 0; j < 8; ++j) o[j] = (short)f2bf(xp[(size_t)j * Nn]);
            bp[mi] = o;
        }
        #pragma unroll
        for (int ci = 0; ci < 4; ++ci)
            #pragma unroll
            for (int mi = 0; mi < 2; ++mi)
                acc[ci][mi] = __builtin_amdgcn_mfma_f32_16x16x32_bf16(
                    af[ci], bp[mi], acc[ci][mi], 0, 0, 0);
    }

    #pragma unroll
    for (int ci = 0; ci < 4; ++ci) {
        #pragma unroll
        for (int rr = 0; rr < 4; ++rr) {
            const int o = wave * 64 + ci * 16 + lq * 4 + rr;
            const float bo = bias[o];
            #pragma unroll
            for (int mi = 0; mi < 2; ++mi) {
                const int n = n0 + mi * 16 + lrow;
                Vout[((size_t)(b * Cc + o)) * Nn + n] = f2bf(acc[ci][mi][rr] + bo);
            }
        }
    }
}

// ---------------------------------------------------------------------------
// Kernel 2: out[b,c,m] = gamma*(sum_n V[c,n]*exp(E[m,n]))/(sum_n exp(E[m,n]))
//                        + 2*X[b,c,m]
// Block: 512 thr, 8 waves (4c x 2m), tile 256c x 64m, BK=64, 64 steps.
// Grid 256 = 64mt x 4b (b = blk&3 -> each batch pinned to 2 XCDs for V-L2).
// Pipeline (manual unroll-2, explicit even/odd register sets, NO rotation):
//   step s consumes Bbuf[s&1] (= exp E(s), staged at step s-1) and V(s)
//   (loaded at step s-1); E loaded at distance 2. One barrier per step.
// ---------------------------------------------------------------------------
__global__ __launch_bounds__(512) void attn_gemm(
    const unsigned short* __restrict__ V, const float* __restrict__ E,
    const float* __restrict__ X, const float* __restrict__ gamma,
    float* __restrict__ Out)
{
    __shared__ unsigned short Bbuf[2][64 * 64];  // exp(E) tile [m][k] bf16, swizzled
    __shared__ float sum_lds[64];

    const int t = threadIdx.x;
    const int blk = blockIdx.x;
    const int b  = blk & 3;
    const int m0 = (blk >> 2) << 6;

    const int wave = t >> 6, lane = t & 63;
    const int wm = wave >> 1, wn = wave & 1;   // wm 0..3 (c), wn 0..1 (m)
    const int lrow = lane & 15, lq = lane >> 4;
    const int l7 = lrow & 7;

    // E staging: thread owns row (t>>3), 8 contiguous floats at col (t&7)*8
    const int erow = t >> 3, eg = t & 7;
    const float* ep = E + (size_t)b * NN2 + (size_t)(m0 + erow) * Nn + eg * 8;
    unsigned short* const bst0 = &Bbuf[0][erow * 64 + ((eg ^ (erow & 7)) << 3)];
    unsigned short* const bst1 = &Bbuf[1][erow * 64 + ((eg ^ (erow & 7)) << 3)];

    // V fragment addressing (per lane): rows wm*64+ci*16+lrow, cols lq*8
    const unsigned short* vbase = V + (size_t)(b * Cc + wm * 64) * Nn;
    int voff[4];
    #pragma unroll
    for (int ci = 0; ci < 4; ++ci) voff[ci] = (ci * 16 + lrow) * Nn + lq * 8;

    f32x4 acc[4][2] = {};
    float sacc = 0.f;

    float4 eA0, eA1, eB0, eB1;
    bf16x8 vA[8], vB[8];

    // ---- prologue ----
    eA0 = *(const float4*)(ep);        eA1 = *(const float4*)(ep + 4);        // E(0)
    eB0 = *(const float4*)(ep + 64);   eB1 = *(const float4*)(ep + 68);       // E(1)
    #pragma unroll
    for (int kk = 0; kk < 2; ++kk)
        #pragma unroll
        for (int ci = 0; ci < 4; ++ci)
            vA[kk * 4 + ci] = *(const bf16x8*)(vbase + voff[ci] + kk * 32);   // V(0)
    expstore(eA0, eA1, bst0, sacc);                                           // Bbuf[0] = expE(0)
    eA0 = *(const float4*)(ep + 128);  eA1 = *(const float4*)(ep + 132);      // E(2)
    __syncthreads();

    // ---- main loop: 32 iterations x 2 steps ----
    for (int k = 0; k < 64; k += 2) {
        // ===== even step s=k: consume vA, Bbuf[0] =====
        {
            bf16x8 bfr[2][2];
            #pragma unroll
            for (int kk = 0; kk < 2; ++kk)
                #pragma unroll
                for (int mi = 0; mi < 2; ++mi) {
                    const int rm = wn * 32 + mi * 16 + lrow;
                    bfr[kk][mi] = *(const bf16x8*)&Bbuf[0][rm * 64 + (((kk * 4 + lq) ^ l7) << 3)];
                }
            const int kv = (k + 1) << 6;                 // V(k+1)
            #pragma unroll
            for (int kk = 0; kk < 2; ++kk)
                #pragma unroll
                for (int ci = 0; ci < 4; ++ci)
                    vB[kk * 4 + ci] = *(const bf16x8*)(vbase + voff[ci] + kv + kk * 32);
            expstore(eB0, eB1, bst1, sacc);              // Bbuf[1] = expE(k+1)
            const int ke = ((k + 3) & 63) << 6;          // E(k+3) (tail wraps, unused)
            eB0 = *(const float4*)(ep + ke); eB1 = *(const float4*)(ep + ke + 4);
            #pragma unroll
            for (int ci = 0; ci < 4; ++ci)
                #pragma unroll
                for (int mi = 0; mi < 2; ++mi)
                    #pragma unroll
                    for (int kk = 0; kk < 2; ++kk)
                        acc[ci][mi] = __builtin_amdgcn_mfma_f32_16x16x32_bf16(
                            vA[kk * 4 + ci], bfr[kk][mi], acc[ci][mi], 0, 0, 0);
            __syncthreads();
        }
        // ===== odd step s=k+1: consume vB, Bbuf[1] =====
        {
            bf16x8 bfr[2][2];
            #pragma unroll
            for (int kk = 0; kk < 2; ++kk)
                #pragma unroll
                for (int mi = 0; mi < 2; ++mi) {
                    const int rm = wn * 32 + mi * 16 + lrow;
                    bfr[kk][mi] = *(const bf16x8*)&Bbuf[1][rm * 64 + (((kk * 4 + lq) ^ l7) << 3)];
                }
            const int kv = ((k + 2) & 63) << 6;          // V(k+2) (tail wraps, unused)
            #pragma unroll
            for (int kk = 0; kk < 2; ++kk)
                #pragma unroll
                for (int ci = 0; ci < 4; ++ci)
                    vA[kk * 4 + ci] = *(const bf16x8*)(vbase + voff[ci] + kv + kk * 32);
            if (k != 62) {                               // no step 64: skip stage (sacc!)
                expstore(eA0, eA1, bst0, sacc);          // Bbuf[0] = expE(k+2)
                const int ke = ((k + 4) & 63) << 6;      // E(k+4)
                eA0 = *(const float4*)(ep + ke); eA1 = *(const float4*)(ep + ke + 4);
            }
            #pragma unroll
            for (int ci = 0; ci < 4; ++ci)
                #pragma unroll
                for (int mi = 0; mi < 2; ++mi)
                    #pragma unroll
                    for (int kk = 0; kk < 2; ++kk)
                        acc[ci][mi] = __builtin_amdgcn_mfma_f32_16x16x32_bf16(
                            vB[kk * 4 + ci], bfr[kk][mi], acc[ci][mi], 0, 0, 0);
            __syncthreads();
        }
    }

    // ---- softmax denominators: 8 threads (t&7) per m-row, same wave ----
    {
        float s = sacc;
        s += __shfl_xor(s, 1);
        s += __shfl_xor(s, 2);
        s += __shfl_xor(s, 4);
        if (eg == 0) sum_lds[erow] = s;
    }
    __syncthreads();

    // ---- epilogue ----
    const float g = gamma[0];
    #pragma unroll
    for (int mi = 0; mi < 2; ++mi) {
        const int mloc = wn * 32 + mi * 16 + lrow;
        const float scale = g / sum_lds[mloc];
        const int m = m0 + mloc;
        #pragma unroll
        for (int ci = 0; ci < 4; ++ci) {
            #pragma unroll
            for (int rr = 0; rr < 4; ++rr) {
                const int c = wm * 64 + ci * 16 + lq * 4 + rr;
                const size_t off = ((size_t)(b * Cc + c)) * Nn + m;
                Out[off] = scale * acc[ci][mi][rr] + 2.0f * X[off];
            }
        }
    }
}

extern "C" void kernel_launch(void* const* d_in, const int* in_sizes, int n_in,
                              void* d_out, int out_size, void* d_ws, size_t ws_size,
                              hipStream_t stream) {
    const float* energy  = (const float*)d_in[0];  // [4,4096,4096]
    const float* x       = (const float*)d_in[1];  // [4,256,64,64]
    const float* value_w = (const float*)d_in[2];  // [256,256]
    const float* value_b = (const float*)d_in[3];  // [256]
    const float* gamma   = (const float*)d_in[4];  // [1]
    float* out = (float*)d_out;
    unsigned short* Vws = (unsigned short*)d_ws;   // 4*256*4096 bf16 = 8 MB

    value_gemm<<<512, 256, 0, stream>>>(x, value_w, value_b, Vws);
    attn_gemm<<<256, 512, 0, stream>>>(Vws, energy, x, gamma, out);
}